// Round 1
// baseline (4191.977 us; speedup 1.0000x reference)
//
#include <hip/hip_runtime.h>
#include <math.h>

#define N_NODES 65536
#define NB 16

// ---- ws layout (float offsets). Partials alias H1 (h1 is dead before set2set). ----
#define H1_OFF    0ull                    // N*128 = 8388608
#define PSEG_OFF  0ull                    // 16384 ints   (aliases H1)
#define PM_OFF    16384ull                // 16384 f
#define PDEN_OFF  32768ull                // 16384 f
#define PNUM_OFF  49152ull                // 16384*256 f  (ends 4243456 < 8388608)
#define H2_OFF    8388608ull              // N*256 = 16777216
#define WC0_OFF   25165824ull             // 128*576  = 73728
#define WC1_OFF   25239552ull             // 256*1152 = 294912
#define WTIH_OFF  25534464ull             // 512*1024 = 524288
#define WTHH_OFF  26058752ull             // 256*1024 = 262144
#define BIAS_OFF  26320896ull             // 1024
#define C_OFF     26321920ull             // 16*256
#define HL_OFF    26326016ull             // 16*256
#define QS_OFF    26330112ull             // 16*512   (ends 26338304 floats = 105.4 MB)

__device__ __forceinline__ float sigm(float x) {
  return __builtin_amdgcn_rcpf(1.0f + __expf(-x));
}

// uniform grid: t[i] = (i-3)*0.4f - 1.0f, i=0..11  (compile-time constants)
__device__ __forceinline__ void bspline_bases(float x, float b8[8]) {
  float t[12];
#pragma unroll
  for (int i = 0; i < 12; ++i) t[i] = (float)(i - 3) * 0.4f - 1.0f;
  float b[11];
#pragma unroll
  for (int i = 0; i < 11; ++i) b[i] = (x >= t[i] && x < t[i + 1]) ? 1.0f : 0.0f;
#pragma unroll
  for (int k = 1; k <= 3; ++k) {
#pragma unroll
    for (int i = 0; i + k < 11; ++i) {
      float invl = 1.0f / (t[i + k] - t[i]);          // folds to constant
      float invr = 1.0f / (t[i + k + 1] - t[i + 1]);  // folds to constant
      b[i] = (x - t[i]) * invl * b[i] + (t[i + k + 1] - x) * invr * b[i + 1];
    }
  }
#pragma unroll
  for (int j = 0; j < 8; ++j) b8[j] = b[j];
}

// ---- prep: pack combined KAN weights (interleaved k = d*9 + {base, 8 bases}),
//      transpose LSTM weights, combine biases, zero LSTM state ----
__global__ __launch_bounds__(256) void prep_kernel(
    const float* __restrict__ bw0, const float* __restrict__ sw0, const float* __restrict__ sc0,
    const float* __restrict__ bw1, const float* __restrict__ sw1, const float* __restrict__ sc1,
    const float* __restrict__ w_ih, const float* __restrict__ w_hh,
    const float* __restrict__ b_ih, const float* __restrict__ b_hh,
    float* __restrict__ ws) {
  int id = blockIdx.x * 256 + threadIdx.x;
  if (id < 73728) {
    int o = id / 576, k = id % 576, d = k / 9, j = k % 9;
    float v = (j == 0) ? bw0[o * 64 + d] : sw0[(o * 64 + d) * 8 + (j - 1)] * sc0[o * 64 + d];
    ws[WC0_OFF + id] = v;
  } else if (id < 368640) {
    int l = id - 73728;
    int o = l / 1152, k = l % 1152, d = k / 9, j = k % 9;
    float v = (j == 0) ? bw1[o * 128 + d] : sw1[(o * 128 + d) * 8 + (j - 1)] * sc1[o * 128 + d];
    ws[WC1_OFF + l] = v;
  } else if (id < 892928) {
    int l = id - 368640; int k = l >> 10, g = l & 1023;
    ws[WTIH_OFF + l] = w_ih[g * 512 + k];
  } else if (id < 1155072) {
    int l = id - 892928; int k = l >> 10, g = l & 1023;
    ws[WTHH_OFF + l] = w_hh[g * 256 + k];
  } else if (id < 1156096) {
    int g = id - 1155072;
    ws[BIAS_OFF + g] = b_ih[g] + b_hh[g];
  } else if (id < 1172480) {
    ws[C_OFF + (id - 1156096)] = 0.0f;  // c, h_lstm, q_star contiguous
  }
}

// ---- fused KAN layer: expand [silu | 8 spline bases] per input dim into LDS, then GEMM ----
template <int IN, int OUT>
__global__ __launch_bounds__(256) void kan_kernel(const float* __restrict__ in,
                                                  const float* __restrict__ Wc,
                                                  float* __restrict__ out) {
  constexpr int K = IN * 9;
  constexpr int STR = K + 4;  // stride%32==4 -> 2-way-max LDS conflict, 16B aligned rows
  __shared__ float A[16 * STR];
  const int tid = threadIdx.x;
  const int n0 = blockIdx.x * 16;
  const float* inb = in + (size_t)n0 * IN;
  for (int task = tid; task < 16 * IN; task += 256) {
    int n = task / IN;          // IN is pow2
    int d = task - n * IN;
    float v = inb[task];        // coalesced
    float* ar = &A[n * STR + d * 9];
    ar[0] = v * sigm(v);
    float b8[8];
    bspline_bases(v, b8);
#pragma unroll
    for (int j = 0; j < 8; ++j) ar[1 + j] = b8[j];
  }
  __syncthreads();
  const int i = tid & 15;       // node within tile
  const int u = tid >> 4;       // 0..15
  const int obase = blockIdx.y * 64 + u * 4;
  const float4* Ar = (const float4*)&A[i * STR];
  const float4* w0 = (const float4*)(Wc + (size_t)(obase + 0) * K);
  const float4* w1 = (const float4*)(Wc + (size_t)(obase + 1) * K);
  const float4* w2 = (const float4*)(Wc + (size_t)(obase + 2) * K);
  const float4* w3 = (const float4*)(Wc + (size_t)(obase + 3) * K);
  float a0 = 0.f, a1 = 0.f, a2 = 0.f, a3 = 0.f;
#pragma unroll 4
  for (int k4 = 0; k4 < K / 4; ++k4) {
    float4 a = Ar[k4];
    float4 q0 = w0[k4], q1 = w1[k4], q2 = w2[k4], q3 = w3[k4];
    a0 += a.x * q0.x + a.y * q0.y + a.z * q0.z + a.w * q0.w;
    a1 += a.x * q1.x + a.y * q1.y + a.z * q1.z + a.w * q1.w;
    a2 += a.x * q2.x + a.y * q2.y + a.z * q2.z + a.w * q2.w;
    a3 += a.x * q3.x + a.y * q3.y + a.z * q3.z + a.w * q3.w;
  }
  *(float4*)(out + (size_t)(n0 + i) * OUT + obase) = make_float4(a0, a1, a2, a3);
}

// ---- LayerNorm over 256 dims, one wave per node, in place ----
__global__ __launch_bounds__(256) void ln_kernel(float* __restrict__ h,
                                                 const float* __restrict__ g,
                                                 const float* __restrict__ b) {
  int gid = blockIdx.x * 256 + threadIdx.x;
  int node = gid >> 6;
  int lane = gid & 63;
  float4* row = (float4*)(h + (size_t)node * 256);
  float4 v = row[lane];
  float s1 = v.x + v.y + v.z + v.w;
  float s2 = v.x * v.x + v.y * v.y + v.z * v.z + v.w * v.w;
#pragma unroll
  for (int off = 32; off; off >>= 1) { s1 += __shfl_xor(s1, off); s2 += __shfl_xor(s2, off); }
  float mu = s1 * (1.0f / 256.0f);
  float var = s2 * (1.0f / 256.0f) - mu * mu;
  float rs = rsqrtf(var + 1e-5f);
  float4 g4 = ((const float4*)g)[lane];
  float4 b4 = ((const float4*)b)[lane];
  v.x = (v.x - mu) * rs * g4.x + b4.x;
  v.y = (v.y - mu) * rs * g4.y + b4.y;
  v.z = (v.z - mu) * rs * g4.z + b4.z;
  v.w = (v.w - mu) * rs * g4.w + b4.w;
  row[lane] = v;
}

// ---- LSTM step: gates = [q_star|h] @ Wt + bias; update c, h (=q). 16 blocks x 1024 ----
__global__ __launch_bounds__(1024) void lstm_kernel(const float* __restrict__ wT_ih,
                                                    const float* __restrict__ wT_hh,
                                                    const float* __restrict__ bias,
                                                    float* __restrict__ c,
                                                    float* __restrict__ hl,
                                                    const float* __restrict__ qstar) {
  int b = blockIdx.x, t = threadIdx.x;
  __shared__ float qs[512], hh[256], gates[1024];
  if (t < 512) qs[t] = qstar[b * 512 + t];
  else if (t < 768) hh[t - 512] = hl[b * 256 + (t - 512)];
  __syncthreads();
  float acc = bias[t];
#pragma unroll 8
  for (int k = 0; k < 512; ++k) acc += qs[k] * wT_ih[k * 1024 + t];
#pragma unroll 8
  for (int k = 0; k < 256; ++k) acc += hh[k] * wT_hh[k * 1024 + t];
  gates[t] = acc;
  __syncthreads();
  if (t < 256) {
    float ig = gates[t], fg = gates[256 + t], gg = gates[512 + t], og = gates[768 + t];
    float cv = sigm(fg) * c[b * 256 + t] + sigm(ig) * tanhf(gg);
    float hv = sigm(og) * tanhf(cv);
    c[b * 256 + t] = cv;
    hl[b * 256 + t] = hv;
  }
}

// ---- flash attention pass: e = h.q[batch], online softmax, per-wave segment partials ----
__global__ __launch_bounds__(256) void attn_pass(const float* __restrict__ h,
                                                 const float* __restrict__ q,
                                                 const int* __restrict__ batch,
                                                 float* __restrict__ pm,
                                                 float* __restrict__ pden,
                                                 int* __restrict__ pseg,
                                                 float* __restrict__ pnum) {
  int w = (blockIdx.x * 256 + threadIdx.x) >> 6;
  int lane = threadIdx.x & 63;
  int node0 = w * 16;
  const float4* h4 = (const float4*)h;
  const float4* q4 = (const float4*)q;
  int slot = 0;
  int cur = batch[node0];
  float m = -INFINITY, den = 0.f;
  float nx = 0.f, ny = 0.f, nz = 0.f, nw = 0.f;
  float4 qv = q4[cur * 64 + lane];
  for (int n = 0; n < 16; ++n) {
    int node = node0 + n;
    int s = batch[node];
    float4 hv = h4[(size_t)node * 64 + lane];
    if (s != cur) {
      int sl = w * 4 + slot;
      if (slot < 4) {
        if (lane == 0) { pseg[sl] = cur; pm[sl] = m; pden[sl] = den; }
        ((float4*)pnum)[(size_t)sl * 64 + lane] = make_float4(nx, ny, nz, nw);
      }
      slot++;
      cur = s; m = -INFINITY; den = 0.f; nx = ny = nz = nw = 0.f;
      qv = q4[cur * 64 + lane];
    }
    float e = hv.x * qv.x + hv.y * qv.y + hv.z * qv.z + hv.w * qv.w;
#pragma unroll
    for (int off = 32; off; off >>= 1) e += __shfl_xor(e, off);
    float mn = fmaxf(m, e);
    float sc = __expf(m - mn);   // first iter: exp(-inf)=0
    float p = __expf(e - mn);
    den = den * sc + p;
    nx = nx * sc + p * hv.x; ny = ny * sc + p * hv.y;
    nz = nz * sc + p * hv.z; nw = nw * sc + p * hv.w;
    m = mn;
  }
  int sl = w * 4 + slot;
  if (slot < 4) {
    if (lane == 0) { pseg[sl] = cur; pm[sl] = m; pden[sl] = den; }
    ((float4*)pnum)[(size_t)sl * 64 + lane] = make_float4(nx, ny, nz, nw);
  }
  slot++;
  for (int s2 = slot; s2 < 4; ++s2)
    if (lane == 0) pseg[w * 4 + s2] = -1;
}

// ---- merge partials per segment (log-sum-exp merge), write q_star = [q, r] ----
__global__ __launch_bounds__(256) void merge_kernel(const int* __restrict__ batch,
                                                    const float* __restrict__ pm,
                                                    const float* __restrict__ pden,
                                                    const int* __restrict__ pseg,
                                                    const float* __restrict__ pnum,
                                                    const float* __restrict__ hl,
                                                    float* __restrict__ qstar) {
  int s = blockIdx.x, tid = threadIdx.x;
  __shared__ float red[256];
  __shared__ int nlohi[2];
  if (tid == 0) {
    int lo = 0, hi = N_NODES;
    while (lo < hi) { int mid = (lo + hi) >> 1; if (batch[mid] < s) lo = mid + 1; else hi = mid; }
    nlohi[0] = lo;
    hi = N_NODES;
    while (lo < hi) { int mid = (lo + hi) >> 1; if (batch[mid] < s + 1) lo = mid + 1; else hi = mid; }
    nlohi[1] = lo;
  }
  __syncthreads();
  int nl = nlohi[0], nh = nlohi[1];
  float r = 0.f;
  if (nh > nl) {
    int sl0 = (nl >> 4) * 4, sl1 = ((nh - 1) >> 4) * 4 + 4;
    float mloc = -INFINITY;
    for (int j = sl0 + tid; j < sl1; j += 256)
      if (pseg[j] == s) mloc = fmaxf(mloc, pm[j]);
    red[tid] = mloc; __syncthreads();
    for (int o = 128; o; o >>= 1) { if (tid < o) red[tid] = fmaxf(red[tid], red[tid + o]); __syncthreads(); }
    float M = red[0]; __syncthreads();
    float dloc = 0.f;
    for (int j = sl0 + tid; j < sl1; j += 256)
      if (pseg[j] == s) dloc += pden[j] * __expf(pm[j] - M);
    red[tid] = dloc; __syncthreads();
    for (int o = 128; o; o >>= 1) { if (tid < o) red[tid] += red[tid + o]; __syncthreads(); }
    float DEN = red[0];
    float acc = 0.f;
    for (int j = sl0; j < sl1; ++j) {
      if (pseg[j] == s) {
        float wgt = __expf(pm[j] - M);
        acc += wgt * pnum[(size_t)j * 256 + tid];  // coalesced
      }
    }
    r = (DEN > 0.f) ? acc / DEN : 0.f;
  }
  qstar[s * 512 + tid] = hl[s * 256 + tid];
  qstar[s * 512 + 256 + tid] = r;
}

// ---- final: out = [q_star(8192) | zeros(1536) | arange(512) | zeros(512)] ----
__global__ __launch_bounds__(256) void final_kernel(const float* __restrict__ qstar,
                                                    float* __restrict__ out) {
  int i = blockIdx.x * 256 + threadIdx.x;
  if (i >= 10752) return;
  float v;
  if (i < 8192) v = qstar[i];
  else if (i < 9728) v = 0.f;
  else if (i < 10240) v = (float)(i - 9728);
  else v = 0.f;
  out[i] = v;
}

extern "C" void kernel_launch(void* const* d_in, const int* in_sizes, int n_in,
                              void* d_out, int out_size, void* d_ws, size_t ws_size,
                              hipStream_t stream) {
  const float* x    = (const float*)d_in[0];
  const int*   batch= (const int*)d_in[3];
  const float* bw0  = (const float*)d_in[4];
  const float* sw0  = (const float*)d_in[5];
  const float* sc0  = (const float*)d_in[6];
  const float* bw1  = (const float*)d_in[7];
  const float* sw1  = (const float*)d_in[8];
  const float* sc1  = (const float*)d_in[9];
  const float* ln_g = (const float*)d_in[10];
  const float* ln_b = (const float*)d_in[11];
  const float* w_ih = (const float*)d_in[12];
  const float* w_hh = (const float*)d_in[13];
  const float* b_ih = (const float*)d_in[14];
  const float* b_hh = (const float*)d_in[15];
  float* ws = (float*)d_ws;

  prep_kernel<<<4580, 256, 0, stream>>>(bw0, sw0, sc0, bw1, sw1, sc1, w_ih, w_hh, b_ih, b_hh, ws);
  kan_kernel<64, 128><<<dim3(4096, 2), 256, 0, stream>>>(x, ws + WC0_OFF, ws + H1_OFF);
  kan_kernel<128, 256><<<dim3(4096, 4), 256, 0, stream>>>(ws + H1_OFF, ws + WC1_OFF, ws + H2_OFF);
  ln_kernel<<<16384, 256, 0, stream>>>(ws + H2_OFF, ln_g, ln_b);
  for (int step = 0; step < 8; ++step) {
    lstm_kernel<<<16, 1024, 0, stream>>>(ws + WTIH_OFF, ws + WTHH_OFF, ws + BIAS_OFF,
                                         ws + C_OFF, ws + HL_OFF, ws + QS_OFF);
    attn_pass<<<1024, 256, 0, stream>>>(ws + H2_OFF, ws + HL_OFF, batch,
                                        ws + PM_OFF, ws + PDEN_OFF,
                                        (int*)(ws + PSEG_OFF), ws + PNUM_OFF);
    merge_kernel<<<16, 256, 0, stream>>>(batch, ws + PM_OFF, ws + PDEN_OFF,
                                         (const int*)(ws + PSEG_OFF), ws + PNUM_OFF,
                                         ws + HL_OFF, ws + QS_OFF);
  }
  final_kernel<<<42, 256, 0, stream>>>(ws + QS_OFF, (float*)d_out);
}

// Round 4
// 1859.402 us; speedup vs baseline: 2.2545x; 2.2545x over previous
//
#include <hip/hip_runtime.h>
#include <math.h>

#define N_NODES 65536
#define NB 16

// ---- ws layout (float offsets). Partials alias H1 (h1 dead before set2set). ----
#define H1_OFF    0ull                    // N*128 f = 8388608
#define PSEG_OFF  0ull                    // 16384 ints (aliases H1)
#define PM_OFF    16384ull
#define PDEN_OFF  32768ull
#define PNUM_OFF  49152ull                // 16384*256 f (ends 4243456 < 8388608)
#define H2_OFF    8388608ull              // N*256 f = 16777216
#define WB0_OFF   25165824ull             // 128*1024 bf16 = 65536 float-slots
#define WB1_OFF   25239552ull             // 256*2048 bf16 = 262144 float-slots
#define WTIH_OFF  25534464ull             // 512*1024 f
#define WTHH_OFF  26058752ull             // 256*1024 f
#define BIAS_OFF  26320896ull             // 1024 f
#define C_OFF     26321920ull             // 16*256
#define HL_OFF    26326016ull             // 16*256
#define QS_OFF    26330112ull             // 16*512

typedef __attribute__((ext_vector_type(8))) short s16x8;
typedef __attribute__((ext_vector_type(4))) float f32x4;

__device__ __forceinline__ float sigm(float x) {
  return __builtin_amdgcn_rcpf(1.0f + __expf(-x));
}

__device__ __forceinline__ short f2bf(float f) {
  union { float f; unsigned u; } v; v.f = f;
  unsigned r = (v.u + 0x7FFFu + ((v.u >> 16) & 1u)) >> 16;
  return (short)r;
}

// uniform grid: t[i] = (i-3)*0.4f - 1.0f, i=0..11  (compile-time constants)
__device__ __forceinline__ void bspline_bases(float x, float b8[8]) {
  float t[12];
#pragma unroll
  for (int i = 0; i < 12; ++i) t[i] = (float)(i - 3) * 0.4f - 1.0f;
  float b[11];
#pragma unroll
  for (int i = 0; i < 11; ++i) b[i] = (x >= t[i] && x < t[i + 1]) ? 1.0f : 0.0f;
#pragma unroll
  for (int k = 1; k <= 3; ++k) {
#pragma unroll
    for (int i = 0; i + k < 11; ++i) {
      float invl = 1.0f / (t[i + k] - t[i]);
      float invr = 1.0f / (t[i + k + 1] - t[i + 1]);
      b[i] = (x - t[i]) * invl * b[i] + (t[i + k + 1] - x) * invr * b[i + 1];
    }
  }
#pragma unroll
  for (int j = 0; j < 8; ++j) b8[j] = b[j];
}

// ---- prep: pack bf16 KAN weights (k = d*16 + j; j=0 silu-base, j=1..8 spline*scaler, j>=9 zero),
//      transpose LSTM weights (fp32), combine biases, zero LSTM state ----
__global__ __launch_bounds__(256) void prep_kernel(
    const float* __restrict__ bw0, const float* __restrict__ sw0, const float* __restrict__ sc0,
    const float* __restrict__ bw1, const float* __restrict__ sw1, const float* __restrict__ sc1,
    const float* __restrict__ w_ih, const float* __restrict__ w_hh,
    const float* __restrict__ b_ih, const float* __restrict__ b_hh,
    float* __restrict__ ws) {
  int id = blockIdx.x * 256 + threadIdx.x;
  if (id < 131072) {                       // Wp0: [128][1024] bf16
    int o = id >> 10, k = id & 1023, d = k >> 4, j = k & 15;
    float v = (j == 0) ? bw0[o * 64 + d]
            : (j < 9)  ? sw0[(o * 64 + d) * 8 + (j - 1)] * sc0[o * 64 + d] : 0.0f;
    ((short*)(ws + WB0_OFF))[id] = f2bf(v);
  } else if (id < 655360) {                // Wp1: [256][2048] bf16
    int l = id - 131072;
    int o = l >> 11, k = l & 2047, d = k >> 4, j = k & 15;
    float v = (j == 0) ? bw1[o * 128 + d]
            : (j < 9)  ? sw1[(o * 128 + d) * 8 + (j - 1)] * sc1[o * 128 + d] : 0.0f;
    ((short*)(ws + WB1_OFF))[l] = f2bf(v);
  } else if (id < 1179648) {
    int l = id - 655360; int k = l >> 10, g = l & 1023;
    ws[WTIH_OFF + l] = w_ih[g * 512 + k];
  } else if (id < 1441792) {
    int l = id - 1179648; int k = l >> 10, g = l & 1023;
    ws[WTHH_OFF + l] = w_hh[g * 256 + k];
  } else if (id < 1442816) {
    int g = id - 1441792;
    ws[BIAS_OFF + g] = b_ih[g] + b_hh[g];
  } else if (id < 1459200) {
    ws[C_OFF + (id - 1442816)] = 0.0f;     // c, h_lstm, q_star contiguous
  }
}

// ---- fused KAN layer via bf16 MFMA: expand [silu|bases|pad] into LDS, 128x128 tile ----
// LDS layout for both A and B tiles: [kgroup(16)][row(128)] of 8 contiguous bf16 (16B slots).
// Fragment read = single ds_read_b128: lane&15 -> row/col, lane>>4 -> kgroup. Conflict-free.
template <int IN, int OUT>
__global__ __launch_bounds__(256, 2) void kan_mfma(const float* __restrict__ in,
                                                   const short* __restrict__ Wp,
                                                   float* __restrict__ out) {
  constexpr int Kp = IN * 16;
  constexpr int CHUNKS = Kp / 128;
  __shared__ s16x8 As[2048];   // 32 KB
  __shared__ s16x8 Bs[2048];   // 32 KB
  const int tid = threadIdx.x;
  const int n0 = blockIdx.x * 128;
  const int nb0 = blockIdx.y * 128;
  const int lane = tid & 63;
  const int wid = tid >> 6;
  const int wr = wid >> 1, wc = wid & 1;
  const int l15 = lane & 15, l4 = lane >> 4;
  const int xn = tid & 127, dh = tid >> 7;   // expansion task mapping

  f32x4 acc[4][4] = {};

  for (int c = 0; c < CHUNKS; ++c) {
    if (c) __syncthreads();   // previous chunk's MFMA done reading LDS
    // stage B chunk: Bs[kg][col] = Wp[nb0+col][c*128 + kg*8 .. +8]
    const short* wbase = Wp + (size_t)nb0 * Kp + c * 128;
#pragma unroll
    for (int i = 0; i < 8; ++i) {
      int s = i * 256 + tid;
      int kg = s >> 7, col = s & 127;
      const short* src = wbase + (size_t)col * Kp + kg * 8;
      __builtin_amdgcn_global_load_lds(
          (const __attribute__((address_space(1))) unsigned int*)src,
          (__attribute__((address_space(3))) unsigned int*)&Bs[s], 16, 0, 0);
    }
    // expand A chunk: rows n0..n0+127, dims d = c*8 .. c*8+7
#pragma unroll
    for (int i = 0; i < 4; ++i) {
      int dl = i * 2 + dh;
      float v = in[(size_t)(n0 + xn) * IN + (c * 8 + dl)];
      float sv = v * sigm(v);
      float b8[8];
      bspline_bases(v, b8);
      s16x8 q0, q1 = {};
      q0[0] = f2bf(sv);
      q0[1] = f2bf(b8[0]); q0[2] = f2bf(b8[1]); q0[3] = f2bf(b8[2]);
      q0[4] = f2bf(b8[3]); q0[5] = f2bf(b8[4]); q0[6] = f2bf(b8[5]);
      q0[7] = f2bf(b8[6]);
      q1[0] = f2bf(b8[7]);
      As[(dl * 2) * 128 + xn] = q0;
      As[(dl * 2 + 1) * 128 + xn] = q1;
    }
    __syncthreads();          // drains vmcnt (global_load_lds) + lgkmcnt before barrier
#pragma unroll
    for (int kk = 0; kk < 4; ++kk) {
      s16x8 a[4], b[4];
#pragma unroll
      for (int mi = 0; mi < 4; ++mi)
        a[mi] = As[(kk * 4 + l4) * 128 + wr * 64 + mi * 16 + l15];
#pragma unroll
      for (int ni = 0; ni < 4; ++ni)
        b[ni] = Bs[(kk * 4 + l4) * 128 + wc * 64 + ni * 16 + l15];
#pragma unroll
      for (int mi = 0; mi < 4; ++mi)
#pragma unroll
        for (int ni = 0; ni < 4; ++ni)
          acc[mi][ni] = __builtin_amdgcn_mfma_f32_16x16x32_bf16(a[mi], b[ni], acc[mi][ni], 0, 0, 0);
    }
  }
  // epilogue: C[m][n], col = lane&15, row = (lane>>4)*4 + reg
#pragma unroll
  for (int mi = 0; mi < 4; ++mi) {
#pragma unroll
    for (int r = 0; r < 4; ++r) {
      int m = wr * 64 + mi * 16 + l4 * 4 + r;
      float* orow = out + (size_t)(n0 + m) * OUT + nb0;
#pragma unroll
      for (int ni = 0; ni < 4; ++ni)
        orow[wc * 64 + ni * 16 + l15] = acc[mi][ni][r];
    }
  }
}

// ---- LayerNorm over 256 dims, one wave per node, in place ----
__global__ __launch_bounds__(256) void ln_kernel(float* __restrict__ h,
                                                 const float* __restrict__ g,
                                                 const float* __restrict__ b) {
  int gid = blockIdx.x * 256 + threadIdx.x;
  int node = gid >> 6;
  int lane = gid & 63;
  float4* row = (float4*)(h + (size_t)node * 256);
  float4 v = row[lane];
  float s1 = v.x + v.y + v.z + v.w;
  float s2 = v.x * v.x + v.y * v.y + v.z * v.z + v.w * v.w;
#pragma unroll
  for (int off = 32; off; off >>= 1) { s1 += __shfl_xor(s1, off); s2 += __shfl_xor(s2, off); }
  float mu = s1 * (1.0f / 256.0f);
  float var = s2 * (1.0f / 256.0f) - mu * mu;
  float rs = rsqrtf(var + 1e-5f);
  float4 g4 = ((const float4*)g)[lane];
  float4 b4 = ((const float4*)b)[lane];
  v.x = (v.x - mu) * rs * g4.x + b4.x;
  v.y = (v.y - mu) * rs * g4.y + b4.y;
  v.z = (v.z - mu) * rs * g4.z + b4.z;
  v.w = (v.w - mu) * rs * g4.w + b4.w;
  row[lane] = v;
}

// ---- LSTM step: gates = [q_star|h] @ Wt + bias; update c, h(=q). 16 blocks x 1024 ----
__global__ __launch_bounds__(1024) void lstm_kernel(const float* __restrict__ wT_ih,
                                                    const float* __restrict__ wT_hh,
                                                    const float* __restrict__ bias,
                                                    float* __restrict__ c,
                                                    float* __restrict__ hl,
                                                    const float* __restrict__ qstar) {
  int b = blockIdx.x, t = threadIdx.x;
  __shared__ float qs[512], hh[256], gates[1024];
  if (t < 512) qs[t] = qstar[b * 512 + t];
  else if (t < 768) hh[t - 512] = hl[b * 256 + (t - 512)];
  __syncthreads();
  float acc = bias[t];
#pragma unroll 8
  for (int k = 0; k < 512; ++k) acc += qs[k] * wT_ih[k * 1024 + t];
#pragma unroll 8
  for (int k = 0; k < 256; ++k) acc += hh[k] * wT_hh[k * 1024 + t];
  gates[t] = acc;
  __syncthreads();
  if (t < 256) {
    float ig = gates[t], fg = gates[256 + t], gg = gates[512 + t], og = gates[768 + t];
    float cv = sigm(fg) * c[b * 256 + t] + sigm(ig) * tanhf(gg);
    float hv = sigm(og) * tanhf(cv);
    c[b * 256 + t] = cv;
    hl[b * 256 + t] = hv;
  }
}

// ---- flash attention pass: e = h.q[batch], online softmax, per-wave segment partials ----
__global__ __launch_bounds__(256) void attn_pass(const float* __restrict__ h,
                                                 const float* __restrict__ q,
                                                 const int* __restrict__ batch,
                                                 float* __restrict__ pm,
                                                 float* __restrict__ pden,
                                                 int* __restrict__ pseg,
                                                 float* __restrict__ pnum) {
  int w = (blockIdx.x * 256 + threadIdx.x) >> 6;
  int lane = threadIdx.x & 63;
  int node0 = w * 16;
  const float4* h4 = (const float4*)h;
  const float4* q4 = (const float4*)q;
  int slot = 0;
  int cur = batch[node0];
  float m = -INFINITY, den = 0.f;
  float nx = 0.f, ny = 0.f, nz = 0.f, nw = 0.f;
  float4 qv = q4[cur * 64 + lane];
  for (int n = 0; n < 16; ++n) {
    int node = node0 + n;
    int s = batch[node];
    float4 hv = h4[(size_t)node * 64 + lane];
    if (s != cur) {
      int sl = w * 4 + slot;
      if (slot < 4) {
        if (lane == 0) { pseg[sl] = cur; pm[sl] = m; pden[sl] = den; }
        ((float4*)pnum)[(size_t)sl * 64 + lane] = make_float4(nx, ny, nz, nw);
      }
      slot++;
      cur = s; m = -INFINITY; den = 0.f; nx = ny = nz = nw = 0.f;
      qv = q4[cur * 64 + lane];
    }
    float e = hv.x * qv.x + hv.y * qv.y + hv.z * qv.z + hv.w * qv.w;
#pragma unroll
    for (int off = 32; off; off >>= 1) e += __shfl_xor(e, off);
    float mn = fmaxf(m, e);
    float sc = __expf(m - mn);
    float p = __expf(e - mn);
    den = den * sc + p;
    nx = nx * sc + p * hv.x; ny = ny * sc + p * hv.y;
    nz = nz * sc + p * hv.z; nw = nw * sc + p * hv.w;
    m = mn;
  }
  int sl = w * 4 + slot;
  if (slot < 4) {
    if (lane == 0) { pseg[sl] = cur; pm[sl] = m; pden[sl] = den; }
    ((float4*)pnum)[(size_t)sl * 64 + lane] = make_float4(nx, ny, nz, nw);
  }
  slot++;
  for (int s2 = slot; s2 < 4; ++s2)
    if (lane == 0) pseg[w * 4 + s2] = -1;
}

// ---- merge partials per segment, write q_star = [q, r] ----
__global__ __launch_bounds__(256) void merge_kernel(const int* __restrict__ batch,
                                                    const float* __restrict__ pm,
                                                    const float* __restrict__ pden,
                                                    const int* __restrict__ pseg,
                                                    const float* __restrict__ pnum,
                                                    const float* __restrict__ hl,
                                                    float* __restrict__ qstar) {
  int s = blockIdx.x, tid = threadIdx.x;
  __shared__ float red[256];
  __shared__ int nlohi[2];
  if (tid == 0) {
    int lo = 0, hi = N_NODES;
    while (lo < hi) { int mid = (lo + hi) >> 1; if (batch[mid] < s) lo = mid + 1; else hi = mid; }
    nlohi[0] = lo;
    hi = N_NODES;
    while (lo < hi) { int mid = (lo + hi) >> 1; if (batch[mid] < s + 1) lo = mid + 1; else hi = mid; }
    nlohi[1] = lo;
  }
  __syncthreads();
  int nl = nlohi[0], nh = nlohi[1];
  float r = 0.f;
  if (nh > nl) {
    int sl0 = (nl >> 4) * 4, sl1 = ((nh - 1) >> 4) * 4 + 4;
    float mloc = -INFINITY;
    for (int j = sl0 + tid; j < sl1; j += 256)
      if (pseg[j] == s) mloc = fmaxf(mloc, pm[j]);
    red[tid] = mloc; __syncthreads();
    for (int o = 128; o; o >>= 1) { if (tid < o) red[tid] = fmaxf(red[tid], red[tid + o]); __syncthreads(); }
    float M = red[0]; __syncthreads();
    float dloc = 0.f;
    for (int j = sl0 + tid; j < sl1; j += 256)
      if (pseg[j] == s) dloc += pden[j] * __expf(pm[j] - M);
    red[tid] = dloc; __syncthreads();
    for (int o = 128; o; o >>= 1) { if (tid < o) red[tid] += red[tid + o]; __syncthreads(); }
    float DEN = red[0];
    float acc = 0.f;
    for (int j = sl0; j < sl1; ++j) {
      if (pseg[j] == s) {
        float wgt = __expf(pm[j] - M);
        acc += wgt * pnum[(size_t)j * 256 + tid];
      }
    }
    r = (DEN > 0.f) ? acc / DEN : 0.f;
  }
  qstar[s * 512 + tid] = hl[s * 256 + tid];
  qstar[s * 512 + 256 + tid] = r;
}

// ---- final: out = [q_star(8192) | zeros(1536) | arange(512) | zeros(512)] ----
__global__ __launch_bounds__(256) void final_kernel(const float* __restrict__ qstar,
                                                    float* __restrict__ out) {
  int i = blockIdx.x * 256 + threadIdx.x;
  if (i >= 10752) return;
  float v;
  if (i < 8192) v = qstar[i];
  else if (i < 9728) v = 0.f;
  else if (i < 10240) v = (float)(i - 9728);
  else v = 0.f;
  out[i] = v;
}

extern "C" void kernel_launch(void* const* d_in, const int* in_sizes, int n_in,
                              void* d_out, int out_size, void* d_ws, size_t ws_size,
                              hipStream_t stream) {
  const float* x    = (const float*)d_in[0];
  const int*   batch= (const int*)d_in[3];
  const float* bw0  = (const float*)d_in[4];
  const float* sw0  = (const float*)d_in[5];
  const float* sc0  = (const float*)d_in[6];
  const float* bw1  = (const float*)d_in[7];
  const float* sw1  = (const float*)d_in[8];
  const float* sc1  = (const float*)d_in[9];
  const float* ln_g = (const float*)d_in[10];
  const float* ln_b = (const float*)d_in[11];
  const float* w_ih = (const float*)d_in[12];
  const float* w_hh = (const float*)d_in[13];
  const float* b_ih = (const float*)d_in[14];
  const float* b_hh = (const float*)d_in[15];
  float* ws = (float*)d_ws;

  prep_kernel<<<5700, 256, 0, stream>>>(bw0, sw0, sc0, bw1, sw1, sc1, w_ih, w_hh, b_ih, b_hh, ws);
  kan_mfma<64, 128><<<dim3(512, 1), 256, 0, stream>>>(x, (const short*)(ws + WB0_OFF), ws + H1_OFF);
  kan_mfma<128, 256><<<dim3(512, 2), 256, 0, stream>>>(ws + H1_OFF, (const short*)(ws + WB1_OFF), ws + H2_OFF);
  ln_kernel<<<16384, 256, 0, stream>>>(ws + H2_OFF, ln_g, ln_b);
  for (int step = 0; step < 8; ++step) {
    lstm_kernel<<<16, 1024, 0, stream>>>(ws + WTIH_OFF, ws + WTHH_OFF, ws + BIAS_OFF,
                                         ws + C_OFF, ws + HL_OFF, ws + QS_OFF);
    attn_pass<<<1024, 256, 0, stream>>>(ws + H2_OFF, ws + HL_OFF, batch,
                                        ws + PM_OFF, ws + PDEN_OFF,
                                        (int*)(ws + PSEG_OFF), ws + PNUM_OFF);
    merge_kernel<<<16, 256, 0, stream>>>(batch, ws + PM_OFF, ws + PDEN_OFF,
                                         (const int*)(ws + PSEG_OFF), ws + PNUM_OFF,
                                         ws + HL_OFF, ws + QS_OFF);
  }
  final_kernel<<<42, 256, 0, stream>>>(ws + QS_OFF, (float*)d_out);
}

// Round 5
// 823.690 us; speedup vs baseline: 5.0893x; 2.2574x over previous
//
#include <hip/hip_runtime.h>
#include <math.h>

#define N_NODES 65536
#define NB 16
#define BPS 64   // blocks per segment in attn

// ---- ws layout (float offsets). Partials alias H1 (h1 dead after kan1). ----
#define H1_OFF    0ull                    // N*128 f = 8388608
#define PM_OFF    0ull                    // 1024 f (aliases H1, used post-kan1)
#define PDEN_OFF  1024ull                 // 1024 f
#define PNUM_OFF  16384ull                // 1024*256 f = 262144 (ends 278528 < 8388608)
#define H2_OFF    8388608ull              // N*256 f = 16777216
#define WB0_OFF   25165824ull             // 128*1024 bf16 = 65536 float-slots
#define SEGB_OFF  25231360ull             // 17 ints (gap between WB0 and WB1)
#define WB1_OFF   25239552ull             // 256*2048 bf16 = 262144 float-slots
#define WTIH_OFF  25534464ull             // 512*1024 f
#define WTHH_OFF  26058752ull             // 256*1024 f
#define BIAS_OFF  26320896ull             // 1024 f
#define C_OFF     26321920ull             // 16*256
#define HL_OFF    26326016ull             // 16*256
#define QS_OFF    26330112ull             // 16*512

typedef __attribute__((ext_vector_type(8))) short s16x8;
typedef __attribute__((ext_vector_type(4))) float f32x4;

__device__ __forceinline__ float sigm(float x) {
  return __builtin_amdgcn_rcpf(1.0f + __expf(-x));
}

__device__ __forceinline__ short f2bf(float f) {
  union { float f; unsigned u; } v; v.f = f;
  unsigned r = (v.u + 0x7FFFu + ((v.u >> 16) & 1u)) >> 16;
  return (short)r;
}

// uniform grid: t[i] = (i-3)*0.4f - 1.0f, i=0..11  (compile-time constants)
__device__ __forceinline__ void bspline_bases(float x, float b8[8]) {
  float t[12];
#pragma unroll
  for (int i = 0; i < 12; ++i) t[i] = (float)(i - 3) * 0.4f - 1.0f;
  float b[11];
#pragma unroll
  for (int i = 0; i < 11; ++i) b[i] = (x >= t[i] && x < t[i + 1]) ? 1.0f : 0.0f;
#pragma unroll
  for (int k = 1; k <= 3; ++k) {
#pragma unroll
    for (int i = 0; i + k < 11; ++i) {
      float invl = 1.0f / (t[i + k] - t[i]);
      float invr = 1.0f / (t[i + k + 1] - t[i + 1]);
      b[i] = (x - t[i]) * invl * b[i] + (t[i + k + 1] - x) * invr * b[i + 1];
    }
  }
#pragma unroll
  for (int j = 0; j < 8; ++j) b8[j] = b[j];
}

// ---- prep: pack bf16 KAN weights, transpose LSTM weights, combine biases,
//      zero LSTM state, segment boundaries (batch sorted -> binary search) ----
__global__ __launch_bounds__(256) void prep_kernel(
    const float* __restrict__ bw0, const float* __restrict__ sw0, const float* __restrict__ sc0,
    const float* __restrict__ bw1, const float* __restrict__ sw1, const float* __restrict__ sc1,
    const float* __restrict__ w_ih, const float* __restrict__ w_hh,
    const float* __restrict__ b_ih, const float* __restrict__ b_hh,
    const int* __restrict__ batch,
    float* __restrict__ ws) {
  int id = blockIdx.x * 256 + threadIdx.x;
  if (id < 131072) {                       // Wp0: [128][1024] bf16
    int o = id >> 10, k = id & 1023, d = k >> 4, j = k & 15;
    float v = (j == 0) ? bw0[o * 64 + d]
            : (j < 9)  ? sw0[(o * 64 + d) * 8 + (j - 1)] * sc0[o * 64 + d] : 0.0f;
    ((short*)(ws + WB0_OFF))[id] = f2bf(v);
  } else if (id < 655360) {                // Wp1: [256][2048] bf16
    int l = id - 131072;
    int o = l >> 11, k = l & 2047, d = k >> 4, j = k & 15;
    float v = (j == 0) ? bw1[o * 128 + d]
            : (j < 9)  ? sw1[(o * 128 + d) * 8 + (j - 1)] * sc1[o * 128 + d] : 0.0f;
    ((short*)(ws + WB1_OFF))[l] = f2bf(v);
  } else if (id < 1179648) {
    int l = id - 655360; int k = l >> 10, g = l & 1023;
    ws[WTIH_OFF + l] = w_ih[g * 512 + k];
  } else if (id < 1441792) {
    int l = id - 1179648; int k = l >> 10, g = l & 1023;
    ws[WTHH_OFF + l] = w_hh[g * 256 + k];
  } else if (id < 1442816) {
    int g = id - 1441792;
    ws[BIAS_OFF + g] = b_ih[g] + b_hh[g];
  } else if (id < 1459200) {
    ws[C_OFF + (id - 1442816)] = 0.0f;     // c, h_lstm, q_star contiguous
  } else if (id < 1459217) {
    int s = id - 1459200;                  // boundary[s] = first idx with batch >= s
    int lo = 0, hi = N_NODES;
    while (lo < hi) { int mid = (lo + hi) >> 1; if (batch[mid] < s) lo = mid + 1; else hi = mid; }
    ((int*)(ws + SEGB_OFF))[s] = lo;
  }
}

// ---- fused KAN layer via bf16 MFMA: expand [silu|bases|pad] into LDS, 128x128 tile ----
template <int IN, int OUT>
__global__ __launch_bounds__(256, 2) void kan_mfma(const float* __restrict__ in,
                                                   const short* __restrict__ Wp,
                                                   float* __restrict__ out) {
  constexpr int Kp = IN * 16;
  constexpr int CHUNKS = Kp / 128;
  __shared__ s16x8 As[2048];   // 32 KB
  __shared__ s16x8 Bs[2048];   // 32 KB
  const int tid = threadIdx.x;
  const int n0 = blockIdx.x * 128;
  const int nb0 = blockIdx.y * 128;
  const int lane = tid & 63;
  const int wid = tid >> 6;
  const int wr = wid >> 1, wc = wid & 1;
  const int l15 = lane & 15, l4 = lane >> 4;
  const int xn = tid & 127, dh = tid >> 7;

  f32x4 acc[4][4] = {};

  for (int c = 0; c < CHUNKS; ++c) {
    if (c) __syncthreads();
    const short* wbase = Wp + (size_t)nb0 * Kp + c * 128;
#pragma unroll
    for (int i = 0; i < 8; ++i) {
      int s = i * 256 + tid;
      int kg = s >> 7, col = s & 127;
      const short* src = wbase + (size_t)col * Kp + kg * 8;
      __builtin_amdgcn_global_load_lds(
          (const __attribute__((address_space(1))) unsigned int*)src,
          (__attribute__((address_space(3))) unsigned int*)&Bs[s], 16, 0, 0);
    }
#pragma unroll
    for (int i = 0; i < 4; ++i) {
      int dl = i * 2 + dh;
      float v = in[(size_t)(n0 + xn) * IN + (c * 8 + dl)];
      float sv = v * sigm(v);
      float b8[8];
      bspline_bases(v, b8);
      s16x8 q0, q1 = {};
      q0[0] = f2bf(sv);
      q0[1] = f2bf(b8[0]); q0[2] = f2bf(b8[1]); q0[3] = f2bf(b8[2]);
      q0[4] = f2bf(b8[3]); q0[5] = f2bf(b8[4]); q0[6] = f2bf(b8[5]);
      q0[7] = f2bf(b8[6]);
      q1[0] = f2bf(b8[7]);
      As[(dl * 2) * 128 + xn] = q0;
      As[(dl * 2 + 1) * 128 + xn] = q1;
    }
    __syncthreads();
#pragma unroll
    for (int kk = 0; kk < 4; ++kk) {
      s16x8 a[4], b[4];
#pragma unroll
      for (int mi = 0; mi < 4; ++mi)
        a[mi] = As[(kk * 4 + l4) * 128 + wr * 64 + mi * 16 + l15];
#pragma unroll
      for (int ni = 0; ni < 4; ++ni)
        b[ni] = Bs[(kk * 4 + l4) * 128 + wc * 64 + ni * 16 + l15];
#pragma unroll
      for (int mi = 0; mi < 4; ++mi)
#pragma unroll
        for (int ni = 0; ni < 4; ++ni)
          acc[mi][ni] = __builtin_amdgcn_mfma_f32_16x16x32_bf16(a[mi], b[ni], acc[mi][ni], 0, 0, 0);
    }
  }
#pragma unroll
  for (int mi = 0; mi < 4; ++mi) {
#pragma unroll
    for (int r = 0; r < 4; ++r) {
      int m = wr * 64 + mi * 16 + l4 * 4 + r;
      float* orow = out + (size_t)(n0 + m) * OUT + nb0;
#pragma unroll
      for (int ni = 0; ni < 4; ++ni)
        orow[wc * 64 + ni * 16 + l15] = acc[mi][ni][r];
    }
  }
}

// ---- LayerNorm over 256 dims, one wave per node, in place ----
__global__ __launch_bounds__(256) void ln_kernel(float* __restrict__ h,
                                                 const float* __restrict__ g,
                                                 const float* __restrict__ b) {
  int gid = blockIdx.x * 256 + threadIdx.x;
  int node = gid >> 6;
  int lane = gid & 63;
  float4* row = (float4*)(h + (size_t)node * 256);
  float4 v = row[lane];
  float s1 = v.x + v.y + v.z + v.w;
  float s2 = v.x * v.x + v.y * v.y + v.z * v.z + v.w * v.w;
#pragma unroll
  for (int off = 32; off; off >>= 1) { s1 += __shfl_xor(s1, off); s2 += __shfl_xor(s2, off); }
  float mu = s1 * (1.0f / 256.0f);
  float var = s2 * (1.0f / 256.0f) - mu * mu;
  float rs = rsqrtf(var + 1e-5f);
  float4 g4 = ((const float4*)g)[lane];
  float4 b4 = ((const float4*)b)[lane];
  v.x = (v.x - mu) * rs * g4.x + b4.x;
  v.y = (v.y - mu) * rs * g4.y + b4.y;
  v.z = (v.z - mu) * rs * g4.z + b4.z;
  v.w = (v.w - mu) * rs * g4.w + b4.w;
  row[lane] = v;
}

// ---- LSTM step: 64 blocks; block (b, quarter q): all 4 gate types for cells q*64..q*64+63 ----
__global__ __launch_bounds__(256) void lstm_kernel(const float* __restrict__ wT_ih,
                                                   const float* __restrict__ wT_hh,
                                                   const float* __restrict__ bias,
                                                   float* __restrict__ c,
                                                   float* __restrict__ hl,
                                                   const float* __restrict__ qstar) {
  int blk = blockIdx.x;
  int b = blk >> 2, q = blk & 3;
  int t = threadIdx.x;
  int gtype = t >> 6, cell = q * 64 + (t & 63);
  int g = gtype * 256 + cell;
  __shared__ float qs[512], hh[256], gl[256];
  qs[t] = qstar[b * 512 + t];
  qs[256 + t] = qstar[b * 512 + 256 + t];
  hh[t] = hl[b * 256 + t];
  __syncthreads();
  float acc = bias[g];
#pragma unroll 8
  for (int k = 0; k < 512; ++k) acc += qs[k] * wT_ih[k * 1024 + g];
#pragma unroll 8
  for (int k = 0; k < 256; ++k) acc += hh[k] * wT_hh[k * 1024 + g];
  gl[gtype * 64 + (t & 63)] = acc;
  __syncthreads();
  if (t < 64) {
    int cl = q * 64 + t;
    float ig = gl[t], fg = gl[64 + t], gg = gl[128 + t], og = gl[192 + t];
    float cv = sigm(fg) * c[b * 256 + cl] + sigm(ig) * tanhf(gg);
    float hv = sigm(og) * tanhf(cv);
    c[b * 256 + cl] = cv;
    hl[b * 256 + cl] = hv;
  }
}

// ---- attn: block = (segment s, chunk j). Online softmax over contiguous chunk;
//      4-wave LDS combine -> exactly one partial per block. ----
__global__ __launch_bounds__(256) void attn_kernel(const float* __restrict__ h,
                                                   const float* __restrict__ hl,
                                                   const int* __restrict__ segb,
                                                   float* __restrict__ pm,
                                                   float* __restrict__ pden,
                                                   float* __restrict__ pnum) {
  int blk = blockIdx.x;
  int s = blk >> 6, j = blk & (BPS - 1);
  int lo = segb[s], hi = segb[s + 1];
  int cnt = hi - lo;
  int chunk = (cnt + BPS - 1) >> 6;
  int blo = lo + j * chunk;
  int bhi = min(blo + chunk, hi);
  int tid = threadIdx.x;
  int wv = tid >> 6, lane = tid & 63;
  __shared__ float sm[4], sden[4];
  __shared__ float snum[4][256];
  const float4* h4 = (const float4*)h;
  float4 qv = ((const float4*)hl)[s * 64 + lane];
  float m = -INFINITY, den = 0.f;
  float ax = 0.f, ay = 0.f, az = 0.f, aw = 0.f;
  int n = blo + wv;
  for (; n + 4 < bhi; n += 8) {
    float4 h1 = h4[(size_t)n * 64 + lane];
    float4 h2 = h4[(size_t)(n + 4) * 64 + lane];
    float e1 = h1.x * qv.x + h1.y * qv.y + h1.z * qv.z + h1.w * qv.w;
    float e2 = h2.x * qv.x + h2.y * qv.y + h2.z * qv.z + h2.w * qv.w;
#pragma unroll
    for (int off = 32; off; off >>= 1) { e1 += __shfl_xor(e1, off); e2 += __shfl_xor(e2, off); }
    float mn = fmaxf(m, fmaxf(e1, e2));
    float scl = __expf(m - mn);
    float p1 = __expf(e1 - mn), p2 = __expf(e2 - mn);
    den = den * scl + p1 + p2;
    ax = ax * scl + p1 * h1.x + p2 * h2.x;
    ay = ay * scl + p1 * h1.y + p2 * h2.y;
    az = az * scl + p1 * h1.z + p2 * h2.z;
    aw = aw * scl + p1 * h1.w + p2 * h2.w;
    m = mn;
  }
  for (; n < bhi; n += 4) {
    float4 h1 = h4[(size_t)n * 64 + lane];
    float e1 = h1.x * qv.x + h1.y * qv.y + h1.z * qv.z + h1.w * qv.w;
#pragma unroll
    for (int off = 32; off; off >>= 1) e1 += __shfl_xor(e1, off);
    float mn = fmaxf(m, e1);
    float scl = __expf(m - mn);
    float p1 = __expf(e1 - mn);
    den = den * scl + p1;
    ax = ax * scl + p1 * h1.x;
    ay = ay * scl + p1 * h1.y;
    az = az * scl + p1 * h1.z;
    aw = aw * scl + p1 * h1.w;
    m = mn;
  }
  if (lane == 0) { sm[wv] = m; sden[wv] = den; }
  ((float4*)snum[wv])[lane] = make_float4(ax, ay, az, aw);
  __syncthreads();
  // combine 4 wave-partials; every thread handles one dim t
  float M = fmaxf(fmaxf(sm[0], sm[1]), fmaxf(sm[2], sm[3]));
  float D = 0.f, nm = 0.f;
  if (M > -INFINITY) {
#pragma unroll
    for (int wq = 0; wq < 4; ++wq) {
      float wgt = (sm[wq] == -INFINITY) ? 0.f : __expf(sm[wq] - M);
      D += wgt * sden[wq];
      nm += wgt * snum[wq][tid];
    }
  }
  if (tid == 0) { pm[blk] = M; pden[blk] = D; }
  pnum[(size_t)blk * 256 + tid] = nm;
}

// ---- merge: 16 blocks, 64 coalesced slots each; write q_star = [q, r] ----
__global__ __launch_bounds__(256) void merge_kernel(const float* __restrict__ pm,
                                                    const float* __restrict__ pden,
                                                    const float* __restrict__ pnum,
                                                    const float* __restrict__ hl,
                                                    float* __restrict__ qstar) {
  int s = blockIdx.x, t = threadIdx.x;
  float M = -INFINITY;
#pragma unroll 8
  for (int j = 0; j < BPS; ++j) M = fmaxf(M, pm[s * BPS + j]);
  float den = 0.f, num = 0.f;
#pragma unroll 4
  for (int j = 0; j < BPS; ++j) {
    float mj = pm[s * BPS + j];
    float wgt = (mj == -INFINITY) ? 0.f : __expf(mj - M);
    den += wgt * pden[s * BPS + j];
    num += wgt * pnum[(size_t)(s * BPS + j) * 256 + t];
  }
  float r = (den > 0.f) ? num / den : 0.f;
  qstar[s * 512 + t] = hl[s * 256 + t];
  qstar[s * 512 + 256 + t] = r;
}

// ---- final: out = [q_star(8192) | zeros(1536) | arange(512) | zeros(512)] ----
__global__ __launch_bounds__(256) void final_kernel(const float* __restrict__ qstar,
                                                    float* __restrict__ out) {
  int i = blockIdx.x * 256 + threadIdx.x;
  if (i >= 10752) return;
  float v;
  if (i < 8192) v = qstar[i];
  else if (i < 9728) v = 0.f;
  else if (i < 10240) v = (float)(i - 9728);
  else v = 0.f;
  out[i] = v;
}

extern "C" void kernel_launch(void* const* d_in, const int* in_sizes, int n_in,
                              void* d_out, int out_size, void* d_ws, size_t ws_size,
                              hipStream_t stream) {
  const float* x    = (const float*)d_in[0];
  const int*   batch= (const int*)d_in[3];
  const float* bw0  = (const float*)d_in[4];
  const float* sw0  = (const float*)d_in[5];
  const float* sc0  = (const float*)d_in[6];
  const float* bw1  = (const float*)d_in[7];
  const float* sw1  = (const float*)d_in[8];
  const float* sc1  = (const float*)d_in[9];
  const float* ln_g = (const float*)d_in[10];
  const float* ln_b = (const float*)d_in[11];
  const float* w_ih = (const float*)d_in[12];
  const float* w_hh = (const float*)d_in[13];
  const float* b_ih = (const float*)d_in[14];
  const float* b_hh = (const float*)d_in[15];
  float* ws = (float*)d_ws;

  prep_kernel<<<5701, 256, 0, stream>>>(bw0, sw0, sc0, bw1, sw1, sc1, w_ih, w_hh,
                                        b_ih, b_hh, batch, ws);
  kan_mfma<64, 128><<<dim3(512, 1), 256, 0, stream>>>(x, (const short*)(ws + WB0_OFF), ws + H1_OFF);
  kan_mfma<128, 256><<<dim3(512, 2), 256, 0, stream>>>(ws + H1_OFF, (const short*)(ws + WB1_OFF), ws + H2_OFF);
  ln_kernel<<<16384, 256, 0, stream>>>(ws + H2_OFF, ln_g, ln_b);
  const int* segb = (const int*)(ws + SEGB_OFF);
  for (int step = 0; step < 8; ++step) {
    lstm_kernel<<<64, 256, 0, stream>>>(ws + WTIH_OFF, ws + WTHH_OFF, ws + BIAS_OFF,
                                        ws + C_OFF, ws + HL_OFF, ws + QS_OFF);
    attn_kernel<<<NB * BPS, 256, 0, stream>>>(ws + H2_OFF, ws + HL_OFF, segb,
                                              ws + PM_OFF, ws + PDEN_OFF, ws + PNUM_OFF);
    merge_kernel<<<NB, 256, 0, stream>>>(ws + PM_OFF, ws + PDEN_OFF, ws + PNUM_OFF,
                                         ws + HL_OFF, ws + QS_OFF);
  }
  final_kernel<<<42, 256, 0, stream>>>(ws + QS_OFF, (float*)d_out);
}

// Round 6
// 771.599 us; speedup vs baseline: 5.4328x; 1.0675x over previous
//
#include <hip/hip_runtime.h>
#include <math.h>

#define N_NODES 65536
#define NB 16
#define BPS 64   // blocks per segment in attn

// ---- ws layout (float offsets). Weights/state low; tensors high.
//      Split mode appends AF (dense bf16 features); fused mode does not need it. ----
#define WD0_OFF   0ull          // dense W0: 128*576 bf16 = 36864 f
#define WD1_OFF   36864ull      // dense W1: 256*1152 bf16 = 147456 f
#define WB0_OFF   184320ull     // padded W0: 128*1024 bf16 = 65536 f (fallback)
#define WB1_OFF   249856ull     // padded W1: 256*2048 bf16 = 262144 f (fallback)
#define WTIH_OFF  512000ull     // 512*1024 f
#define WTHH_OFF  1036288ull    // 256*1024 f
#define BIAS_OFF  1298432ull    // 1024 f
#define C_OFF     1299456ull    // 16*256
#define HL_OFF    1303552ull    // 16*256
#define QS_OFF    1307648ull    // 16*512
#define SEGB_OFF  1315840ull    // 17 ints (+pad)
#define PM_OFF    1315872ull    // 1024 f
#define PDEN_OFF  1316896ull    // 1024 f
#define PNUM_OFF  1317920ull    // 1024*256 f
#define H1_OFF    1580064ull    // N*128 f = 8388608
#define H2_OFF    9968672ull    // N*256 f = 16777216
#define AF_OFF    26745888ull   // 65536*1152 bf16 = 37748736 f (split only; Af0 fits too)
#define FUSED_NEED_F  26745888ull
#define SPLIT_NEED_F  64494624ull

typedef __attribute__((ext_vector_type(8))) short s16x8;
typedef __attribute__((ext_vector_type(4))) float f32x4;

__device__ __forceinline__ float sigm(float x) {
  return __builtin_amdgcn_rcpf(1.0f + __expf(-x));
}

__device__ __forceinline__ short f2bf(float f) {
  union { float f; unsigned u; } v; v.f = f;
  unsigned r = (v.u + 0x7FFFu + ((v.u >> 16) & 1u)) >> 16;
  return (short)r;
}

// uniform grid: t[i] = (i-3)*0.4f - 1.0f, i=0..11  (compile-time constants)
__device__ __forceinline__ void bspline_bases(float x, float b8[8]) {
  float t[12];
#pragma unroll
  for (int i = 0; i < 12; ++i) t[i] = (float)(i - 3) * 0.4f - 1.0f;
  float b[11];
#pragma unroll
  for (int i = 0; i < 11; ++i) b[i] = (x >= t[i] && x < t[i + 1]) ? 1.0f : 0.0f;
#pragma unroll
  for (int k = 1; k <= 3; ++k) {
#pragma unroll
    for (int i = 0; i + k < 11; ++i) {
      float invl = 1.0f / (t[i + k] - t[i]);
      float invr = 1.0f / (t[i + k + 1] - t[i + 1]);
      b[i] = (x - t[i]) * invl * b[i] + (t[i + k + 1] - x) * invr * b[i + 1];
    }
  }
#pragma unroll
  for (int j = 0; j < 8; ++j) b8[j] = b[j];
}

// ---- prep: pack dense + padded bf16 KAN weights, transpose LSTM weights,
//      combine biases, zero LSTM state, segment boundaries ----
__global__ __launch_bounds__(256) void prep_kernel(
    const float* __restrict__ bw0, const float* __restrict__ sw0, const float* __restrict__ sc0,
    const float* __restrict__ bw1, const float* __restrict__ sw1, const float* __restrict__ sc1,
    const float* __restrict__ w_ih, const float* __restrict__ w_hh,
    const float* __restrict__ b_ih, const float* __restrict__ b_hh,
    const int* __restrict__ batch,
    float* __restrict__ ws) {
  int id = blockIdx.x * 256 + threadIdx.x;
  if (id < 73728) {                        // Wd0 dense: [128][576]
    int o = id / 576, k = id % 576;
    float v;
    if (k < 64) v = bw0[o * 64 + k];
    else { int kk = k - 64, d = kk >> 3, j = kk & 7;
           v = sw0[(o * 64 + d) * 8 + j] * sc0[o * 64 + d]; }
    ((short*)(ws + WD0_OFF))[id] = f2bf(v);
  } else if (id < 368640) {                // Wd1 dense: [256][1152]
    int l = id - 73728;
    int o = l / 1152, k = l % 1152;
    float v;
    if (k < 128) v = bw1[o * 128 + k];
    else { int kk = k - 128, d = kk >> 3, j = kk & 7;
           v = sw1[(o * 128 + d) * 8 + j] * sc1[o * 128 + d]; }
    ((short*)(ws + WD1_OFF))[l] = f2bf(v);
  } else if (id < 499712) {                // Wp0 padded: [128][1024]
    int l = id - 368640;
    int o = l >> 10, k = l & 1023, d = k >> 4, j = k & 15;
    float v = (j == 0) ? bw0[o * 64 + d]
            : (j < 9)  ? sw0[(o * 64 + d) * 8 + (j - 1)] * sc0[o * 64 + d] : 0.0f;
    ((short*)(ws + WB0_OFF))[l] = f2bf(v);
  } else if (id < 1024000) {               // Wp1 padded: [256][2048]
    int l = id - 499712;
    int o = l >> 11, k = l & 2047, d = k >> 4, j = k & 15;
    float v = (j == 0) ? bw1[o * 128 + d]
            : (j < 9)  ? sw1[(o * 128 + d) * 8 + (j - 1)] * sc1[o * 128 + d] : 0.0f;
    ((short*)(ws + WB1_OFF))[l] = f2bf(v);
  } else if (id < 1548288) {
    int l = id - 1024000; int k = l >> 10, g = l & 1023;
    ws[WTIH_OFF + l] = w_ih[g * 512 + k];
  } else if (id < 1810432) {
    int l = id - 1548288; int k = l >> 10, g = l & 1023;
    ws[WTHH_OFF + l] = w_hh[g * 256 + k];
  } else if (id < 1811456) {
    int g = id - 1810432;
    ws[BIAS_OFF + g] = b_ih[g] + b_hh[g];
  } else if (id < 1827840) {
    ws[C_OFF + (id - 1811456)] = 0.0f;     // c, h_lstm, q_star contiguous
  } else if (id < 1827857) {
    int s = id - 1827840;                  // boundary[s] = first idx with batch >= s
    int lo = 0, hi = N_NODES;
    while (lo < hi) { int mid = (lo + hi) >> 1; if (batch[mid] < s) lo = mid + 1; else hi = mid; }
    ((int*)(ws + SEGB_OFF))[s] = lo;
  }
}

// ---- expansion: x[N][IN] f32 -> Af[N][9*IN] bf16 dense: [silu(d) d<IN | bases d*8+j] ----
template <int IN>
__global__ __launch_bounds__(256) void expand_kernel(const float* __restrict__ in,
                                                     short* __restrict__ Af) {
  constexpr int RS = 9 * IN;
  const int total = N_NODES * IN;
  for (int id = blockIdx.x * 256 + threadIdx.x; id < total; id += gridDim.x * 256) {
    int n = id / IN;             // IN pow2 -> shift
    int d = id & (IN - 1);
    float v = in[id];
    float sv = v * sigm(v);
    float b8[8];
    bspline_bases(v, b8);
    short* rowp = Af + (size_t)n * RS;
    rowp[d] = f2bf(sv);
    s16x8 q;
#pragma unroll
    for (int j = 0; j < 8; ++j) q[j] = f2bf(b8[j]);
    ((s16x8*)(rowp + IN))[d] = q;   // 16B aligned, coalesced
  }
}

// ---- pure GEMM: out[N][OUT] = A[N][K]bf16 @ W[OUT][K]bf16^T. BK=96, 128x128 tile. ----
// LDS: [kgroup(12)][row(128)] of 16B; fragment = 1 ds_read_b128, conflict-free.
template <int K, int OUT>
__global__ __launch_bounds__(256, 2) void gemm_mfma(const short* __restrict__ A,
                                                    const short* __restrict__ Wp,
                                                    float* __restrict__ out) {
  constexpr int CHUNKS = K / 96;
  __shared__ s16x8 As[1536];   // 24 KB
  __shared__ s16x8 Bs[1536];   // 24 KB
  const int tid = threadIdx.x;
  const int n0 = blockIdx.x * 128;
  const int nb0 = blockIdx.y * 128;
  const int lane = tid & 63;
  const int wid = tid >> 6;
  const int wr = wid >> 1, wc = wid & 1;
  const int l15 = lane & 15, l4 = lane >> 4;

  f32x4 acc[4][4] = {};

  for (int c = 0; c < CHUNKS; ++c) {
    if (c) __syncthreads();
    const short* abase = A + (size_t)n0 * K + c * 96;
    const short* bbase = Wp + (size_t)nb0 * K + c * 96;
#pragma unroll
    for (int i = 0; i < 6; ++i) {
      int s = i * 256 + tid;
      int kg = s >> 7, row = s & 127;
      __builtin_amdgcn_global_load_lds(
          (const __attribute__((address_space(1))) unsigned int*)(abase + (size_t)row * K + kg * 8),
          (__attribute__((address_space(3))) unsigned int*)&As[s], 16, 0, 0);
      __builtin_amdgcn_global_load_lds(
          (const __attribute__((address_space(1))) unsigned int*)(bbase + (size_t)row * K + kg * 8),
          (__attribute__((address_space(3))) unsigned int*)&Bs[s], 16, 0, 0);
    }
    __syncthreads();   // drains vmcnt before any wave reads LDS
#pragma unroll
    for (int kk = 0; kk < 3; ++kk) {
      s16x8 a[4], b[4];
#pragma unroll
      for (int mi = 0; mi < 4; ++mi)
        a[mi] = As[(kk * 4 + l4) * 128 + wr * 64 + mi * 16 + l15];
#pragma unroll
      for (int ni = 0; ni < 4; ++ni)
        b[ni] = Bs[(kk * 4 + l4) * 128 + wc * 64 + ni * 16 + l15];
#pragma unroll
      for (int mi = 0; mi < 4; ++mi)
#pragma unroll
        for (int ni = 0; ni < 4; ++ni)
          acc[mi][ni] = __builtin_amdgcn_mfma_f32_16x16x32_bf16(a[mi], b[ni], acc[mi][ni], 0, 0, 0);
    }
  }
  // epilogue: C col = lane&15, row = (lane>>4)*4 + reg
#pragma unroll
  for (int mi = 0; mi < 4; ++mi) {
#pragma unroll
    for (int r = 0; r < 4; ++r) {
      int m = wr * 64 + mi * 16 + l4 * 4 + r;
      float* orow = out + (size_t)(n0 + m) * OUT + nb0;
#pragma unroll
      for (int ni = 0; ni < 4; ++ni)
        orow[wc * 64 + ni * 16 + l15] = acc[mi][ni][r];
    }
  }
}

// ---- fused KAN (fallback when ws too small for split path); padded K=16/dim ----
template <int IN, int OUT>
__global__ __launch_bounds__(256, 2) void kan_mfma(const float* __restrict__ in,
                                                   const short* __restrict__ Wp,
                                                   float* __restrict__ out) {
  constexpr int Kp = IN * 16;
  constexpr int CHUNKS = Kp / 128;
  __shared__ s16x8 As[2048];
  __shared__ s16x8 Bs[2048];
  const int tid = threadIdx.x;
  const int n0 = blockIdx.x * 128;
  const int nb0 = blockIdx.y * 128;
  const int lane = tid & 63;
  const int wid = tid >> 6;
  const int wr = wid >> 1, wc = wid & 1;
  const int l15 = lane & 15, l4 = lane >> 4;
  const int xn = tid & 127, dh = tid >> 7;

  f32x4 acc[4][4] = {};

  for (int c = 0; c < CHUNKS; ++c) {
    if (c) __syncthreads();
    const short* wbase = Wp + (size_t)nb0 * Kp + c * 128;
#pragma unroll
    for (int i = 0; i < 8; ++i) {
      int s = i * 256 + tid;
      int kg = s >> 7, col = s & 127;
      const short* src = wbase + (size_t)col * Kp + kg * 8;
      __builtin_amdgcn_global_load_lds(
          (const __attribute__((address_space(1))) unsigned int*)src,
          (__attribute__((address_space(3))) unsigned int*)&Bs[s], 16, 0, 0);
    }
#pragma unroll
    for (int i = 0; i < 4; ++i) {
      int dl = i * 2 + dh;
      float v = in[(size_t)(n0 + xn) * IN + (c * 8 + dl)];
      float sv = v * sigm(v);
      float b8[8];
      bspline_bases(v, b8);
      s16x8 q0, q1 = {};
      q0[0] = f2bf(sv);
      q0[1] = f2bf(b8[0]); q0[2] = f2bf(b8[1]); q0[3] = f2bf(b8[2]);
      q0[4] = f2bf(b8[3]); q0[5] = f2bf(b8[4]); q0[6] = f2bf(b8[5]);
      q0[7] = f2bf(b8[6]);
      q1[0] = f2bf(b8[7]);
      As[(dl * 2) * 128 + xn] = q0;
      As[(dl * 2 + 1) * 128 + xn] = q1;
    }
    __syncthreads();
#pragma unroll
    for (int kk = 0; kk < 4; ++kk) {
      s16x8 a[4], b[4];
#pragma unroll
      for (int mi = 0; mi < 4; ++mi)
        a[mi] = As[(kk * 4 + l4) * 128 + wr * 64 + mi * 16 + l15];
#pragma unroll
      for (int ni = 0; ni < 4; ++ni)
        b[ni] = Bs[(kk * 4 + l4) * 128 + wc * 64 + ni * 16 + l15];
#pragma unroll
      for (int mi = 0; mi < 4; ++mi)
#pragma unroll
        for (int ni = 0; ni < 4; ++ni)
          acc[mi][ni] = __builtin_amdgcn_mfma_f32_16x16x32_bf16(a[mi], b[ni], acc[mi][ni], 0, 0, 0);
    }
  }
#pragma unroll
  for (int mi = 0; mi < 4; ++mi) {
#pragma unroll
    for (int r = 0; r < 4; ++r) {
      int m = wr * 64 + mi * 16 + l4 * 4 + r;
      float* orow = out + (size_t)(n0 + m) * OUT + nb0;
#pragma unroll
      for (int ni = 0; ni < 4; ++ni)
        orow[wc * 64 + ni * 16 + l15] = acc[mi][ni][r];
    }
  }
}

// ---- LayerNorm over 256 dims, one wave per node, in place ----
__global__ __launch_bounds__(256) void ln_kernel(float* __restrict__ h,
                                                 const float* __restrict__ g,
                                                 const float* __restrict__ b) {
  int gid = blockIdx.x * 256 + threadIdx.x;
  int node = gid >> 6;
  int lane = gid & 63;
  float4* row = (float4*)(h + (size_t)node * 256);
  float4 v = row[lane];
  float s1 = v.x + v.y + v.z + v.w;
  float s2 = v.x * v.x + v.y * v.y + v.z * v.z + v.w * v.w;
#pragma unroll
  for (int off = 32; off; off >>= 1) { s1 += __shfl_xor(s1, off); s2 += __shfl_xor(s2, off); }
  float mu = s1 * (1.0f / 256.0f);
  float var = s2 * (1.0f / 256.0f) - mu * mu;
  float rs = rsqrtf(var + 1e-5f);
  float4 g4 = ((const float4*)g)[lane];
  float4 b4 = ((const float4*)b)[lane];
  v.x = (v.x - mu) * rs * g4.x + b4.x;
  v.y = (v.y - mu) * rs * g4.y + b4.y;
  v.z = (v.z - mu) * rs * g4.z + b4.z;
  v.w = (v.w - mu) * rs * g4.w + b4.w;
  row[lane] = v;
}

// ---- LSTM step: 64 blocks; block (b, quarter q) ----
__global__ __launch_bounds__(256) void lstm_kernel(const float* __restrict__ wT_ih,
                                                   const float* __restrict__ wT_hh,
                                                   const float* __restrict__ bias,
                                                   float* __restrict__ c,
                                                   float* __restrict__ hl,
                                                   const float* __restrict__ qstar) {
  int blk = blockIdx.x;
  int b = blk >> 2, q = blk & 3;
  int t = threadIdx.x;
  int gtype = t >> 6, cell = q * 64 + (t & 63);
  int g = gtype * 256 + cell;
  __shared__ float qs[512], hh[256], gl[256];
  qs[t] = qstar[b * 512 + t];
  qs[256 + t] = qstar[b * 512 + 256 + t];
  hh[t] = hl[b * 256 + t];
  __syncthreads();
  float acc = bias[g];
#pragma unroll 8
  for (int k = 0; k < 512; ++k) acc += qs[k] * wT_ih[k * 1024 + g];
#pragma unroll 8
  for (int k = 0; k < 256; ++k) acc += hh[k] * wT_hh[k * 1024 + g];
  gl[gtype * 64 + (t & 63)] = acc;
  __syncthreads();
  if (t < 64) {
    int cl = q * 64 + t;
    float ig = gl[t], fg = gl[64 + t], gg = gl[128 + t], og = gl[192 + t];
    float cv = sigm(fg) * c[b * 256 + cl] + sigm(ig) * tanhf(gg);
    float hv = sigm(og) * tanhf(cv);
    c[b * 256 + cl] = cv;
    hl[b * 256 + cl] = hv;
  }
}

// ---- attn: block = (segment s, chunk j); one partial per block ----
__global__ __launch_bounds__(256) void attn_kernel(const float* __restrict__ h,
                                                   const float* __restrict__ hl,
                                                   const int* __restrict__ segb,
                                                   float* __restrict__ pm,
                                                   float* __restrict__ pden,
                                                   float* __restrict__ pnum) {
  int blk = blockIdx.x;
  int s = blk >> 6, j = blk & (BPS - 1);
  int lo = segb[s], hi = segb[s + 1];
  int cnt = hi - lo;
  int chunk = (cnt + BPS - 1) >> 6;
  int blo = lo + j * chunk;
  int bhi = min(blo + chunk, hi);
  int tid = threadIdx.x;
  int wv = tid >> 6, lane = tid & 63;
  __shared__ float sm[4], sden[4];
  __shared__ float snum[4][256];
  const float4* h4 = (const float4*)h;
  float4 qv = ((const float4*)hl)[s * 64 + lane];
  float m = -INFINITY, den = 0.f;
  float ax = 0.f, ay = 0.f, az = 0.f, aw = 0.f;
  int n = blo + wv;
  for (; n + 4 < bhi; n += 8) {
    float4 h1 = h4[(size_t)n * 64 + lane];
    float4 h2 = h4[(size_t)(n + 4) * 64 + lane];
    float e1 = h1.x * qv.x + h1.y * qv.y + h1.z * qv.z + h1.w * qv.w;
    float e2 = h2.x * qv.x + h2.y * qv.y + h2.z * qv.z + h2.w * qv.w;
#pragma unroll
    for (int off = 32; off; off >>= 1) { e1 += __shfl_xor(e1, off); e2 += __shfl_xor(e2, off); }
    float mn = fmaxf(m, fmaxf(e1, e2));
    float scl = __expf(m - mn);
    float p1 = __expf(e1 - mn), p2 = __expf(e2 - mn);
    den = den * scl + p1 + p2;
    ax = ax * scl + p1 * h1.x + p2 * h2.x;
    ay = ay * scl + p1 * h1.y + p2 * h2.y;
    az = az * scl + p1 * h1.z + p2 * h2.z;
    aw = aw * scl + p1 * h1.w + p2 * h2.w;
    m = mn;
  }
  for (; n < bhi; n += 4) {
    float4 h1 = h4[(size_t)n * 64 + lane];
    float e1 = h1.x * qv.x + h1.y * qv.y + h1.z * qv.z + h1.w * qv.w;
#pragma unroll
    for (int off = 32; off; off >>= 1) e1 += __shfl_xor(e1, off);
    float mn = fmaxf(m, e1);
    float scl = __expf(m - mn);
    float p1 = __expf(e1 - mn);
    den = den * scl + p1;
    ax = ax * scl + p1 * h1.x;
    ay = ay * scl + p1 * h1.y;
    az = az * scl + p1 * h1.z;
    aw = aw * scl + p1 * h1.w;
    m = mn;
  }
  if (lane == 0) { sm[wv] = m; sden[wv] = den; }
  ((float4*)snum[wv])[lane] = make_float4(ax, ay, az, aw);
  __syncthreads();
  float M = fmaxf(fmaxf(sm[0], sm[1]), fmaxf(sm[2], sm[3]));
  float D = 0.f, nm = 0.f;
  if (M > -INFINITY) {
#pragma unroll
    for (int wq = 0; wq < 4; ++wq) {
      float wgt = (sm[wq] == -INFINITY) ? 0.f : __expf(sm[wq] - M);
      D += wgt * sden[wq];
      nm += wgt * snum[wq][tid];
    }
  }
  if (tid == 0) { pm[blk] = M; pden[blk] = D; }
  pnum[(size_t)blk * 256 + tid] = nm;
}

// ---- merge: 16 blocks, 64 coalesced slots each; write q_star = [q, r] ----
__global__ __launch_bounds__(256) void merge_kernel(const float* __restrict__ pm,
                                                    const float* __restrict__ pden,
                                                    const float* __restrict__ pnum,
                                                    const float* __restrict__ hl,
                                                    float* __restrict__ qstar) {
  int s = blockIdx.x, t = threadIdx.x;
  float M = -INFINITY;
#pragma unroll 8
  for (int j = 0; j < BPS; ++j) M = fmaxf(M, pm[s * BPS + j]);
  float den = 0.f, num = 0.f;
#pragma unroll 4
  for (int j = 0; j < BPS; ++j) {
    float mj = pm[s * BPS + j];
    float wgt = (mj == -INFINITY) ? 0.f : __expf(mj - M);
    den += wgt * pden[s * BPS + j];
    num += wgt * pnum[(size_t)(s * BPS + j) * 256 + t];
  }
  float r = (den > 0.f) ? num / den : 0.f;
  qstar[s * 512 + t] = hl[s * 256 + t];
  qstar[s * 512 + 256 + t] = r;
}

// ---- final: out = [q_star(8192) | zeros(1536) | arange(512) | zeros(512)] ----
__global__ __launch_bounds__(256) void final_kernel(const float* __restrict__ qstar,
                                                    float* __restrict__ out) {
  int i = blockIdx.x * 256 + threadIdx.x;
  if (i >= 10752) return;
  float v;
  if (i < 8192) v = qstar[i];
  else if (i < 9728) v = 0.f;
  else if (i < 10240) v = (float)(i - 9728);
  else v = 0.f;
  out[i] = v;
}

extern "C" void kernel_launch(void* const* d_in, const int* in_sizes, int n_in,
                              void* d_out, int out_size, void* d_ws, size_t ws_size,
                              hipStream_t stream) {
  const float* x    = (const float*)d_in[0];
  const int*   batch= (const int*)d_in[3];
  const float* bw0  = (const float*)d_in[4];
  const float* sw0  = (const float*)d_in[5];
  const float* sc0  = (const float*)d_in[6];
  const float* bw1  = (const float*)d_in[7];
  const float* sw1  = (const float*)d_in[8];
  const float* sc1  = (const float*)d_in[9];
  const float* ln_g = (const float*)d_in[10];
  const float* ln_b = (const float*)d_in[11];
  const float* w_ih = (const float*)d_in[12];
  const float* w_hh = (const float*)d_in[13];
  const float* b_ih = (const float*)d_in[14];
  const float* b_hh = (const float*)d_in[15];
  float* ws = (float*)d_ws;
  const bool split = ws_size >= SPLIT_NEED_F * 4ull;  // constant per session -> graph-safe

  prep_kernel<<<7141, 256, 0, stream>>>(bw0, sw0, sc0, bw1, sw1, sc1, w_ih, w_hh,
                                        b_ih, b_hh, batch, ws);
  if (split) {
    short* Af = (short*)(ws + AF_OFF);
    expand_kernel<64><<<2048, 256, 0, stream>>>(x, Af);
    gemm_mfma<576, 128><<<dim3(512, 1), 256, 0, stream>>>(Af, (const short*)(ws + WD0_OFF), ws + H1_OFF);
    expand_kernel<128><<<2048, 256, 0, stream>>>(ws + H1_OFF, Af);
    gemm_mfma<1152, 256><<<dim3(512, 2), 256, 0, stream>>>(Af, (const short*)(ws + WD1_OFF), ws + H2_OFF);
  } else {
    kan_mfma<64, 128><<<dim3(512, 1), 256, 0, stream>>>(x, (const short*)(ws + WB0_OFF), ws + H1_OFF);
    kan_mfma<128, 256><<<dim3(512, 2), 256, 0, stream>>>(ws + H1_OFF, (const short*)(ws + WB1_OFF), ws + H2_OFF);
  }
  ln_kernel<<<16384, 256, 0, stream>>>(ws + H2_OFF, ln_g, ln_b);
  const int* segb = (const int*)(ws + SEGB_OFF);
  for (int step = 0; step < 8; ++step) {
    lstm_kernel<<<64, 256, 0, stream>>>(ws + WTIH_OFF, ws + WTHH_OFF, ws + BIAS_OFF,
                                        ws + C_OFF, ws + HL_OFF, ws + QS_OFF);
    attn_kernel<<<NB * BPS, 256, 0, stream>>>(ws + H2_OFF, ws + HL_OFF, segb,
                                              ws + PM_OFF, ws + PDEN_OFF, ws + PNUM_OFF);
    merge_kernel<<<NB, 256, 0, stream>>>(ws + PM_OFF, ws + PDEN_OFF, ws + PNUM_OFF,
                                         ws + HL_OFF, ws + QS_OFF);
  }
  final_kernel<<<42, 256, 0, stream>>>(ws + QS_OFF, (float*)d_out);
}